// Round 16
// baseline (129.877 us; speedup 1.0000x reference)
//
#include <hip/hip_runtime.h>
#include <stdint.h>

// NeZha self-attention, B=4 S=1024 H=1024 NH=16 HD=64 MAX_REL=127.
// rel_pos[q,k,:] == table[clip(k-q,-127,127)+127,:], table is 255x64.
//  - score rel term:  gather from R = Q @ table^T (precomputed global, L2-hot)
//  - ctx rel term:    Pagg @ table (banded prob aggregation; clipped tails in regs)
// v16: R15 + Pagg XOR-swizzle (byte ^= (row&7)<<4, T2): Pagg rows are 512B
//      apart (bank-aligned), so the epilogue Pagg reads were ~16-way conflicted
//      (no ln-dependence in byte-in-row) and band scatters ~4-way. XOR spreads
//      rows across 8 16B slots; zero LDS growth (padding would cost occupancy).

typedef __bf16 bf16x8 __attribute__((ext_vector_type(8)));
typedef float f32x4 __attribute__((ext_vector_type(4)));
typedef uint16_t u16x8 __attribute__((ext_vector_type(8)));
typedef uint16_t u16x4 __attribute__((ext_vector_type(4)));

#define K2E 0.18033688011112042f  // 0.125 * log2(e)

__device__ __forceinline__ float hw_exp2(float x) {
    return __builtin_amdgcn_exp2f(x);  // bare v_exp_f32
}
__device__ __forceinline__ uint16_t f2bf(float f) {
    uint32_t u = __builtin_bit_cast(uint32_t, f);
    return (uint16_t)((u + 0x7FFFu + ((u >> 16) & 1u)) >> 16);
}
__device__ __forceinline__ uint16_t f2bf_rn(float f) {  // hw cvt, RNE
    return __builtin_bit_cast(uint16_t, (__bf16)f);
}
__device__ __forceinline__ float bf2f(uint16_t h) {
    uint32_t u = ((uint32_t)h) << 16;
    return __builtin_bit_cast(float, u);
}
__device__ __forceinline__ f32x4 mfma16(bf16x8 a, bf16x8 b, f32x4 c) {
    return __builtin_amdgcn_mfma_f32_16x16x32_bf16(a, b, c, 0, 0, 0);
}
__device__ __forceinline__ bf16x8 ldg8(const uint16_t* p) {
    return __builtin_bit_cast(bf16x8, *(const u16x8*)p);
}
__device__ __forceinline__ bf16x8 lds8(const void* base, int byteoff) {
    return __builtin_bit_cast(bf16x8, *(const u16x8*)((const char*)base + byteoff));
}

// -------- fused preprocessing: cast hs/Wq/Wk/Wv to bf16 + extract table --------
__global__ void k_cast_all(const float* __restrict__ hs, const float* __restrict__ wq,
                           const float* __restrict__ wk, const float* __restrict__ wv,
                           const float* __restrict__ rel,
                           uint16_t* __restrict__ hs_bf, uint16_t* __restrict__ w_bf,
                           uint16_t* __restrict__ tab, uint16_t* __restrict__ tabT) {
    int b = blockIdx.x;
    if (b >= 3584) {  // table extraction: 64 blocks
        int idx = (b - 3584) * 256 + threadIdx.x;
        int j = idx >> 6, d = idx & 63;
        float v = 0.0f;
        if (j < 255) v = rel[((size_t)512 * 1024 + (512 + j - 127)) * 64 + d];
        uint16_t h = f2bf(v);
        tab[j * 64 + d] = h;       // [256][64]
        tabT[d * 256 + j] = h;     // [64][256]
        return;
    }
    const float* src;
    uint16_t* dst;
    int i;
    if (b < 2048)      { src = hs; dst = hs_bf;           i = b * 256 + threadIdx.x; }
    else if (b < 2560) { src = wq; dst = w_bf;            i = (b - 2048) * 256 + threadIdx.x; }
    else if (b < 3072) { src = wk; dst = w_bf + 1048576;  i = (b - 2560) * 256 + threadIdx.x; }
    else               { src = wv; dst = w_bf + 2097152;  i = (b - 3072) * 256 + threadIdx.x; }
    float4 a = ((const float4*)src)[2 * i];
    float4 c = ((const float4*)src)[2 * i + 1];
    u16x8 o;
    o[0] = f2bf(a.x); o[1] = f2bf(a.y); o[2] = f2bf(a.z); o[3] = f2bf(a.w);
    o[4] = f2bf(c.x); o[5] = f2bf(c.y); o[6] = f2bf(c.z); o[7] = f2bf(c.w);
    ((u16x8*)dst)[i] = o;
}

// ------- fused QKV GEMM, LDS-bounced coalesced epilogue; V pre-transposed -------
// Block swizzle: each XCD owns a contiguous 4-m-block slab (1MB A, L2-resident).
__launch_bounds__(256)
__global__ void k_gemm_qkv3(const uint16_t* __restrict__ A, const uint16_t* __restrict__ Wt,
                            const float* __restrict__ bq, const float* __restrict__ bk,
                            const float* __restrict__ bvp, uint16_t* __restrict__ qout,
                            uint16_t* __restrict__ kout, uint16_t* __restrict__ vt) {
    __shared__ uint16_t Sh[2 * 128 * 64];  // As = Sh, Bs = Sh+8192; epilogue: 32KB bounce
    uint16_t* As = Sh;
    uint16_t* Bs = Sh + 8192;
    int bid = blockIdx.x;
    int xcd = bid & 7, idx = bid >> 3;          // 768 = 8 * 96
    int m0 = (xcd * 4 + (idx & 3)) * 128;       // 4 m-blocks per XCD (A-slab 1MB)
    int n0 = (idx >> 2) * 128;                  // 24 n-blocks
    int tid = threadIdx.x;
    int w = tid >> 6, l = tid & 63, lg = l >> 4, ln = l & 15;
    int wm = w >> 1, wn = w & 1;
    int lrow = tid >> 3, lcol = (tid & 7) * 8;
    f32x4 acc[4][4] = {};
    for (int kt = 0; kt < 16; ++kt) {
        int k0 = kt * 64;
        __syncthreads();
#pragma unroll
        for (int c = 0; c < 4; ++c) {
            int row = c * 32 + lrow;
            __builtin_amdgcn_global_load_lds(
                (const __attribute__((address_space(1))) void*)(A + (size_t)(m0 + row) * 1024 + k0 + lcol),
                (__attribute__((address_space(3))) void*)&As[row * 64 + lcol], 16, 0, 0);
            __builtin_amdgcn_global_load_lds(
                (const __attribute__((address_space(1))) void*)(Wt + (size_t)(n0 + row) * 1024 + k0 + lcol),
                (__attribute__((address_space(3))) void*)&Bs[row * 64 + lcol], 16, 0, 0);
        }
        __syncthreads();
#pragma unroll
        for (int ks = 0; ks < 2; ++ks) {
            bf16x8 af[4], bfr[4];
#pragma unroll
            for (int mi = 0; mi < 4; ++mi)
                af[mi] = ldg8(&As[(wm * 64 + mi * 16 + ln) * 64 + ks * 32 + lg * 8]);
#pragma unroll
            for (int ni = 0; ni < 4; ++ni)
                bfr[ni] = ldg8(&Bs[(wn * 64 + ni * 16 + ln) * 64 + ks * 32 + lg * 8]);
#pragma unroll
            for (int mi = 0; mi < 4; ++mi)
#pragma unroll
                for (int ni = 0; ni < 4; ++ni)
                    acc[mi][ni] = mfma16(af[mi], bfr[ni], acc[mi][ni]);
        }
    }
    int b = m0 >> 10, s0r = m0 & 1023;
    int which = n0 >> 10, nbase = n0 & 1023;  // uniform per block
    __syncthreads();  // all MFMA reads of Sh done; reuse as bounce buffer
    if (which < 2) {
        uint16_t* qk = which == 0 ? qout : kout;
        const float* bp = which == 0 ? bq : bk;
        // T[s2][d2] scalar writes (XOR by s2>>2 spreads lg groups)
#pragma unroll
        for (int ni = 0; ni < 4; ++ni) {
            int d2 = wn * 64 + ni * 16 + ln;
            float bb = bp[nbase + d2];
#pragma unroll
            for (int mi = 0; mi < 4; ++mi)
#pragma unroll
                for (int r = 0; r < 4; ++r) {
                    int s2 = wm * 64 + mi * 16 + lg * 4 + r;
                    *(uint16_t*)((char*)Sh + ((s2 * 256 + d2 * 2) ^ (((s2 >> 2) & 7) << 4))) =
                        f2bf(acc[mi][ni][r] + bb);
                }
        }
        __syncthreads();
        // coalesced: 8 lanes cover one (bh,s)-row's 64 d (128B contiguous)
#pragma unroll
        for (int hh = 0; hh < 2; ++hh) {
            int h = (nbase >> 6) + hh;
#pragma unroll
            for (int i = 0; i < 4; ++i) {
                int s2 = i * 32 + w * 8 + (l >> 3);
                int d2 = hh * 64 + (l & 7) * 8;
                u16x8 vv = *(u16x8*)((char*)Sh + ((s2 * 256 + d2 * 2) ^ (((s2 >> 2) & 7) << 4)));
                *(u16x8*)&qk[(((size_t)(b * 16 + h)) * 1024 + s0r + s2) * 64 + (d2 & 63)] = vv;
            }
        }
    } else {
        // T[d2][s2] u16x4 writes (XOR by d2&7)
#pragma unroll
        for (int ni = 0; ni < 4; ++ni) {
            int d2 = wn * 64 + ni * 16 + ln;
            float bb = bvp[nbase + d2];
#pragma unroll
            for (int mi = 0; mi < 4; ++mi) {
                int s2 = wm * 64 + mi * 16 + lg * 4;
                u16x4 pv;
#pragma unroll
                for (int r = 0; r < 4; ++r) pv[r] = f2bf(acc[mi][ni][r] + bb);
                *(u16x4*)((char*)Sh + ((d2 * 256 + s2 * 2) ^ ((d2 & 7) << 4))) = pv;
            }
        }
        __syncthreads();
        // coalesced: 16 lanes cover one (bh,d)-row's 128 s (256B contiguous)
#pragma unroll
        for (int i = 0; i < 8; ++i) {
            int d2 = i * 16 + w * 4 + (l >> 4);
            int s2 = (l & 15) * 8;
            u16x8 vv = *(u16x8*)((char*)Sh + ((d2 * 256 + s2 * 2) ^ ((d2 & 7) << 4)));
            int nr = nbase + d2;
            int h = nr >> 6, d = nr & 63;
            *(u16x8*)&vt[(((size_t)(b * 16 + h)) * 64 + d) * 1024 + s0r + s2] = vv;
        }
    }
}

// ---------------- R = Q @ table^T : [65536,64] @ [64,256] -> bf16 ----------
// LDS-bounce epilogue: store contiguous 512B row segments (u16x8 coalesced).
__launch_bounds__(256)
__global__ void k_r_gemm(const uint16_t* __restrict__ q, const uint16_t* __restrict__ tab,
                         uint16_t* __restrict__ R) {
    __shared__ uint16_t Qs[64 * 72];     //  9216 B
    __shared__ uint16_t Rbb[64 * 264];   // 33792 B bounce (pad 256->264)
    int m0 = blockIdx.x * 64;
    int tid = threadIdx.x;
    int w = tid >> 6, l = tid & 63, lg = l >> 4, ln = l & 15;
#pragma unroll
    for (int c = 0; c < 2; ++c) {
        int idx = c * 256 + tid; int row = idx >> 3, seg = idx & 7;
        *(u16x8*)&Qs[row * 72 + seg * 8] =
            *(const u16x8*)(q + (size_t)(m0 + row) * 64 + seg * 8);
    }
    __syncthreads();
    bf16x8 aq[4][2];
#pragma unroll
    for (int mi = 0; mi < 4; ++mi)
#pragma unroll
        for (int ks = 0; ks < 2; ++ks)
            aq[mi][ks] = ldg8(&Qs[(mi * 16 + ln) * 72 + ks * 32 + lg * 8]);
    f32x4 acc[4][4] = {};
#pragma unroll
    for (int ni = 0; ni < 4; ++ni) {
        int j = w * 64 + ni * 16 + ln;
#pragma unroll
        for (int ks = 0; ks < 2; ++ks) {
            bf16x8 bt = ldg8(tab + j * 64 + ks * 32 + lg * 8);
#pragma unroll
            for (int mi = 0; mi < 4; ++mi)
                acc[mi][ni] = mfma16(aq[mi][ks], bt, acc[mi][ni]);
        }
    }
    // bounce: Rbb[row][j], row = mi*16+lg*4+r, j = w*64+ni*16+ln
#pragma unroll
    for (int ni = 0; ni < 4; ++ni)
#pragma unroll
        for (int mi = 0; mi < 4; ++mi)
#pragma unroll
            for (int r = 0; r < 4; ++r)
                Rbb[(mi * 16 + lg * 4 + r) * 264 + w * 64 + ni * 16 + ln] =
                    f2bf(acc[mi][ni][r]);
    __syncthreads();
    // coalesced store: each row is 512B contiguous in R; 2048 16B-chunks, 8 iters
#pragma unroll
    for (int it = 0; it < 8; ++it) {
        int idx = it * 256 + tid;
        int row = idx >> 5, c = idx & 31;
        u16x8 vv = *(u16x8*)&Rbb[row * 264 + c * 8];
        *(u16x8*)&R[(size_t)(m0 + row) * 256 + c * 8] = vv;
    }
}

// ---- per-group softmax (NO-MAX, exp2): rel add (wave-uniform cls),
//      P = exp2((s+rel)*K2E), Pagg scatter (XOR-swizzled), pack P into
//      canonical PV A-fragment words ----
__device__ __forceinline__ void softmax_grp(
    const f32x4 (&acc)[4], int kt, int qbase, int ln, const uint16_t* __restrict__ Rrow,
    float rel_lo2, float rel_hi2, uint16_t* prow, int lg, int xm,
    float& lloc, float& slo, float& shi, uint32_t (&pk)[4][2]) {
    int cls = (kt * 64 - (qbase + 15) >= 127) ? 2
            : ((kt * 64 + 63 - qbase <= -127) ? 0 : 1);
    int qg = qbase + ln;
    float sv[16];
    if (cls == 2) {
#pragma unroll
        for (int m = 0; m < 4; ++m)
#pragma unroll
            for (int r = 0; r < 4; ++r) sv[m * 4 + r] = fmaf(acc[m][r], K2E, rel_hi2);
    } else if (cls == 0) {
#pragma unroll
        for (int m = 0; m < 4; ++m)
#pragma unroll
            for (int r = 0; r < 4; ++r) sv[m * 4 + r] = fmaf(acc[m][r], K2E, rel_lo2);
    } else {
#pragma unroll
        for (int m = 0; m < 4; ++m) {
            int base = kt * 64 + (m >> 1) * 32 + lg * 8 + (m & 1) * 4 - qg;  // k(m,r)-qg
#pragma unroll
            for (int r = 0; r < 4; ++r) {
                int dj = base + r;
                int djc = dj < -127 ? -127 : (dj > 127 ? 127 : dj);
                float rel = bf2f(Rrow[djc + 127]);  // global, L2-hot
                sv[m * 4 + r] = (acc[m][r] + rel) * K2E;
            }
        }
    }
    float pm[4];
    if (cls == 1) {
#pragma unroll
        for (int m = 0; m < 4; ++m) {
            int base = kt * 64 + (m >> 1) * 32 + lg * 8 + (m & 1) * 4 - qg;
            uint32_t w0 = 0, w1 = 0;
            float ps = 0.f;
#pragma unroll
            for (int r = 0; r < 4; ++r) {
                float P = hw_exp2(sv[m * 4 + r]);
                ps += P;
                uint32_t h = f2bf_rn(P);
                int dj = base + r;
                if (dj <= -127) slo += P;
                else if (dj >= 127) shi += P;
                else *(uint16_t*)((char*)prow + ((((dj + 127) << 1)) ^ xm)) = (uint16_t)h;
                if (r < 2) w0 |= h << (16 * r); else w1 |= h << (16 * (r - 2));
            }
            pm[m] = ps;
            pk[m][0] = w0; pk[m][1] = w1;
        }
    } else {
#pragma unroll
        for (int m = 0; m < 4; ++m) {
            uint32_t w0 = 0, w1 = 0;
            float ps = 0.f;
#pragma unroll
            for (int r = 0; r < 4; ++r) {
                float P = hw_exp2(sv[m * 4 + r]);
                ps += P;
                uint32_t h = f2bf_rn(P);
                if (r < 2) w0 |= h << (16 * r); else w1 |= h << (16 * (r - 2));
            }
            pm[m] = ps;
            pk[m][0] = w0; pk[m][1] = w1;
        }
        float ts = (pm[0] + pm[1]) + (pm[2] + pm[3]);
        if (cls == 2) shi += ts; else slo += ts;
    }
    lloc += (pm[0] + pm[1]) + (pm[2] + pm[3]);  // 4-way partials -> short chain
}

// ---------------- fused attention: QBLK=128, 2 q-groups per wave ----------------
// (R9 structure: K+V staged each tile, reg-prefetch next tile, 2 barriers/tile)
__launch_bounds__(256, 2)
__global__ void k_attn_fused(const uint16_t* __restrict__ qb, const uint16_t* __restrict__ kb,
                             const uint16_t* __restrict__ vtb, const uint16_t* __restrict__ Rb,
                             const uint16_t* __restrict__ tabT, float* __restrict__ out) {
    __shared__ uint16_t Pagg[128 * 256];  // 65536 B, rows wave-private, XOR-swizzled
    __shared__ uint16_t Kb[64 * 64];      //  8192 B, slotK-swizzled [k][d]
    __shared__ uint16_t Vb[64 * 64];      //  8192 B, (row&7)-swizzled V^T [d][k]
    int bid = blockIdx.x;
    bid = (bid & 7) * 64 + (bid >> 3);    // XCD-bijective swizzle (512 wgs)
    int bh = bid >> 3, q0 = (bid & 7) * 128;
    int tid = threadIdx.x;
    int w = tid >> 6, l = tid & 63, lg = l >> 4, ln = l & 15;
    int qbaseA = q0 + w * 16, qbaseB = qbaseA + 64;
    int qA = qbaseA + ln, qB = qA + 64;   // this lane's two softmax q-rows
    int xm = (ln & 7) << 4;               // Pagg row swizzle mask (16B granularity)
    bf16x8 qfA[2], qfB[2];
    {
        const uint16_t* qr = qb + ((size_t)bh * 1024 + qA) * 64;
        qfA[0] = ldg8(qr + lg * 8); qfA[1] = ldg8(qr + 32 + lg * 8);
        qr += 64 * 64;
        qfB[0] = ldg8(qr + lg * 8); qfB[1] = ldg8(qr + 32 + lg * 8);
    }
    const uint16_t* RrowA = Rb + ((size_t)bh * 1024 + qA) * 256;
    const uint16_t* RrowB = RrowA + 64 * 256;
    uint16_t* prowA = &Pagg[(w * 16 + ln) * 256];
    uint16_t* prowB = &Pagg[(64 + w * 16 + ln) * 256];
    {   // zero this wave's 32 Pagg rows (swizzle is a within-row permutation)
        u16x8* pa = (u16x8*)&Pagg[(w * 16) * 256];
        u16x8* pb2 = (u16x8*)&Pagg[(64 + w * 16) * 256];
#pragma unroll
        for (int i = 0; i < 8; ++i) { pa[i * 64 + l] = (u16x8)0; pb2[i * 64 + l] = (u16x8)0; }
    }
    float relA_lo = bf2f(RrowA[0]) * K2E, relA_hi = bf2f(RrowA[254]) * K2E;
    float relB_lo = bf2f(RrowB[0]) * K2E, relB_hi = bf2f(RrowB[254]) * K2E;
    // staging geometry (16B chunks; rows 0..31 chunk0, 32..63 chunk1)
    const int r0 = tid >> 3, c16 = tid & 7;
    const int r1 = 32 + r0;
    const int slotK0 = (r0 & 3) | ((r0 >> 1) & 4), slotK1 = (r1 & 3) | ((r1 >> 1) & 4);
    const int waK0 = (r0 * 128 + c16 * 16) ^ (slotK0 << 4);
    const int waK1 = (r1 * 128 + c16 * 16) ^ (slotK1 << 4);
    const int waV0 = (r0 * 128 + c16 * 16) ^ ((r0 & 7) << 4);
    const int waV1 = (r1 * 128 + c16 * 16) ^ ((r1 & 7) << 4);
    const uint16_t* kt_base = kb + ((size_t)bh * 1024) * 64;
    const uint16_t* vt_base = vtb + (size_t)bh * 64 * 1024;
    // prefetch tile 0
    u16x8 kc0 = *(const u16x8*)(kt_base + (size_t)r0 * 64 + c16 * 8);
    u16x8 kc1 = *(const u16x8*)(kt_base + (size_t)r1 * 64 + c16 * 8);
    u16x8 vc0 = *(const u16x8*)(vt_base + (size_t)r0 * 1024 + c16 * 8);
    u16x8 vc1 = *(const u16x8*)(vt_base + (size_t)r1 * 1024 + c16 * 8);
    float llocA = 0.f, sloA = 0.f, shiA = 0.f;
    float llocB = 0.f, sloB = 0.f, shiB = 0.f;
    f32x4 oaccA[4] = {}, oaccB[4] = {};
    for (int kt = 0; kt < 16; ++kt) {
        __syncthreads();  // previous tile's LDS reads complete
        *(u16x8*)((char*)Kb + waK0) = kc0;
        *(u16x8*)((char*)Kb + waK1) = kc1;
        *(u16x8*)((char*)Vb + waV0) = vc0;
        *(u16x8*)((char*)Vb + waV1) = vc1;
        __syncthreads();  // tile kt visible
        if (kt < 15) {    // prefetch kt+1; latency hides under compute
            const uint16_t* kn = kt_base + (size_t)(kt + 1) * 64 * 64;
            const uint16_t* vn = vt_base + (kt + 1) * 64;
            kc0 = *(const u16x8*)(kn + (size_t)r0 * 64 + c16 * 8);
            kc1 = *(const u16x8*)(kn + (size_t)r1 * 64 + c16 * 8);
            vc0 = *(const u16x8*)(vn + (size_t)r0 * 1024 + c16 * 8);
            vc1 = *(const u16x8*)(vn + (size_t)r1 * 1024 + c16 * 8);
        }
        // QK^T with pi-permuted k-rows; each K-fragment feeds BOTH q-groups
        f32x4 accA[4] = {}, accB[4] = {};
        __builtin_amdgcn_s_setprio(1);
#pragma unroll
        for (int m = 0; m < 4; ++m) {
            int rowp = ((m >> 1) << 5) + ((ln >> 2) << 3) + ((m & 1) << 2) + (ln & 3);
            // slotK(rowp) == ln&7 -> uniform bank pattern
            bf16x8 a0 = lds8(Kb, (rowp * 128 + lg * 16) ^ ((ln & 7) << 4));
            bf16x8 a1 = lds8(Kb, (rowp * 128 + 64 + lg * 16) ^ ((ln & 7) << 4));
            accA[m] = mfma16(a0, qfA[0], accA[m]);
            accA[m] = mfma16(a1, qfA[1], accA[m]);
            accB[m] = mfma16(a0, qfB[0], accB[m]);
            accB[m] = mfma16(a1, qfB[1], accB[m]);
        }
        __builtin_amdgcn_s_setprio(0);
        uint32_t pkA[4][2], pkB[4][2];
        softmax_grp(accA, kt, qbaseA, ln, RrowA, relA_lo, relA_hi, prowA, lg, xm,
                    llocA, sloA, shiA, pkA);
        softmax_grp(accB, kt, qbaseB, ln, RrowB, relB_lo, relB_hi, prowB, lg, xm,
                    llocB, sloB, shiB, pkB);
        // O += P @ V: A-fragments are register renames of pk (canonical layout)
        __builtin_amdgcn_s_setprio(1);
#pragma unroll
        for (int ks = 0; ks < 2; ++ks) {
            uint32_t fa[4] = {pkA[2 * ks][0], pkA[2 * ks][1], pkA[2 * ks + 1][0], pkA[2 * ks + 1][1]};
            uint32_t fb[4] = {pkB[2 * ks][0], pkB[2 * ks][1], pkB[2 * ks + 1][0], pkB[2 * ks + 1][1]};
            bf16x8 apA = __builtin_bit_cast(bf16x8, fa);
            bf16x8 apB = __builtin_bit_cast(bf16x8, fb);
#pragma unroll
            for (int nt = 0; nt < 4; ++nt) {
                int row = nt * 16 + ln;
                bf16x8 bv = lds8(Vb, (row * 128 + (ks * 4 + lg) * 16) ^ ((ln & 7) << 4));
                oaccA[nt] = mfma16(apA, bv, oaccA[nt]);
                oaccB[nt] = mfma16(apB, bv, oaccB[nt]);
            }
        }
        __builtin_amdgcn_s_setprio(0);
    }
    llocA += __shfl_xor(llocA, 16); llocA += __shfl_xor(llocA, 32);
    sloA  += __shfl_xor(sloA, 16);  sloA  += __shfl_xor(sloA, 32);
    shiA  += __shfl_xor(shiA, 16);  shiA  += __shfl_xor(shiA, 32);
    llocB += __shfl_xor(llocB, 16); llocB += __shfl_xor(llocB, 32);
    sloB  += __shfl_xor(sloB, 16);  sloB  += __shfl_xor(sloB, 32);
    shiB  += __shfl_xor(shiB, 16);  shiB  += __shfl_xor(shiB, 32);
    if (lg == 0) {
        *(uint16_t*)((char*)prowA + (0 ^ xm))   = f2bf(sloA);
        *(uint16_t*)((char*)prowA + (508 ^ xm)) = f2bf(shiA);
        *(uint16_t*)((char*)prowB + (0 ^ xm))   = f2bf(sloB);
        *(uint16_t*)((char*)prowB + (508 ^ xm)) = f2bf(shiB);
    }
    // O += Pagg @ table (B^T = tabT[d][j]); bt shared by both groups
#pragma unroll
    for (int ks8 = 0; ks8 < 8; ++ks8) {
        bf16x8 apA = lds8(prowA, (ks8 * 64 + lg * 16) ^ xm);
        bf16x8 apB = lds8(prowB, (ks8 * 64 + lg * 16) ^ xm);
#pragma unroll
        for (int nt = 0; nt < 4; ++nt) {
            bf16x8 bt = ldg8(tabT + (size_t)(nt * 16 + ln) * 256 + ks8 * 32 + lg * 8);
            oaccA[nt] = mfma16(apA, bt, oaccA[nt]);
            oaccB[nt] = mfma16(apB, bt, oaccB[nt]);
        }
    }
    float rinvA[4], rinvB[4];
#pragma unroll
    for (int r = 0; r < 4; ++r) {
        rinvA[r] = 1.0f / __shfl(llocA, lg * 4 + r);
        rinvB[r] = 1.0f / __shfl(llocB, lg * 4 + r);
    }
    int b = bh >> 4, h = bh & 15;
#pragma unroll
    for (int nt = 0; nt < 4; ++nt) {
#pragma unroll
        for (int r = 0; r < 4; ++r) {
            int qoA = q0 + w * 16 + lg * 4 + r;
            out[((size_t)b * 1024 + qoA) * 1024 + h * 64 + nt * 16 + ln] = oaccA[nt][r] * rinvA[r];
            out[((size_t)b * 1024 + qoA + 64) * 1024 + h * 64 + nt * 16 + ln] = oaccB[nt][r] * rinvB[r];
        }
    }
}

extern "C" void kernel_launch(void* const* d_in, const int* in_sizes, int n_in,
                              void* d_out, int out_size, void* d_ws, size_t ws_size,
                              hipStream_t stream) {
    const float* hs  = (const float*)d_in[0];
    const float* Wq  = (const float*)d_in[1];
    const float* bq  = (const float*)d_in[2];
    const float* Wk  = (const float*)d_in[3];
    const float* bk  = (const float*)d_in[4];
    const float* Wv  = (const float*)d_in[5];
    const float* bv  = (const float*)d_in[6];
    const float* rel = (const float*)d_in[7];
    float* out = (float*)d_out;
    char* ws = (char*)d_ws;

    uint16_t* hs_bf = (uint16_t*)(ws);                // 8 MB   [4096][1024]
    uint16_t* W_bf  = (uint16_t*)(ws + 8388608);      // 6 MB   [3072][1024]
    uint16_t* q_bf  = (uint16_t*)(ws + 14680064);     // 8 MB   [64][1024][64]
    uint16_t* k_bf  = (uint16_t*)(ws + 23068672);     // 8 MB   [64][1024][64]
    uint16_t* vt_bf = (uint16_t*)(ws + 31457280);     // 8 MB   [64][64][1024]
    uint16_t* R_bf  = (uint16_t*)(ws + 48234496);     // 32 MB  [65536][256]
    uint16_t* tab   = (uint16_t*)(ws + 81788928);     // 32 KB  [256][64]
    uint16_t* tabT  = (uint16_t*)(ws + 81821696);     // 32 KB  [64][256]

    k_cast_all<<<3648, 256, 0, stream>>>(hs, Wq, Wk, Wv, rel, hs_bf, W_bf, tab, tabT);

    k_gemm_qkv3<<<768, 256, 0, stream>>>(hs_bf, W_bf, bq, bk, bv, q_bf, k_bf, vt_bf);
    k_r_gemm<<<1024, 256, 0, stream>>>(q_bf, tab, R_bf);

    k_attn_fused<<<512, 256, 0, stream>>>(q_bf, k_bf, vt_bf, R_bf, tabT, out);
}

// Round 17
// 127.735 us; speedup vs baseline: 1.0168x; 1.0168x over previous
//
#include <hip/hip_runtime.h>
#include <stdint.h>

// NeZha self-attention, B=4 S=1024 H=1024 NH=16 HD=64 MAX_REL=127.
// rel_pos[q,k,:] == table[clip(k-q,-127,127)+127,:], table is 255x64.
//  - score rel term:  gather from R = Q @ table^T (precomputed global, L2-hot)
//  - ctx rel term:    Pagg @ table (banded prob aggregation; clipped tails in regs)
// v17 == v15 exactly (session best, 128.6us): R16's Pagg XOR-swizzle was neutral
//      (epilogue LDS reads are hidden under the barrier convoy -> T2 regime-gate),
//      reverted. Pipeline: fused cast+table -> fused QKV GEMM (XCD m-slab,
//      gload_lds, LDS-bounce epilogue, V pre-transposed) -> R GEMM (bounce
//      epilogue) -> fused attention (QBLK=128, 2 q-groups/wave, K+V staged,
//      pi-permuted QK^T -> zero-shuffle PV, NO-MAX exp2 softmax, setprio).

typedef __bf16 bf16x8 __attribute__((ext_vector_type(8)));
typedef float f32x4 __attribute__((ext_vector_type(4)));
typedef uint16_t u16x8 __attribute__((ext_vector_type(8)));
typedef uint16_t u16x4 __attribute__((ext_vector_type(4)));

#define K2E 0.18033688011112042f  // 0.125 * log2(e)

__device__ __forceinline__ float hw_exp2(float x) {
    return __builtin_amdgcn_exp2f(x);  // bare v_exp_f32
}
__device__ __forceinline__ uint16_t f2bf(float f) {
    uint32_t u = __builtin_bit_cast(uint32_t, f);
    return (uint16_t)((u + 0x7FFFu + ((u >> 16) & 1u)) >> 16);
}
__device__ __forceinline__ uint16_t f2bf_rn(float f) {  // hw cvt, RNE
    return __builtin_bit_cast(uint16_t, (__bf16)f);
}
__device__ __forceinline__ float bf2f(uint16_t h) {
    uint32_t u = ((uint32_t)h) << 16;
    return __builtin_bit_cast(float, u);
}
__device__ __forceinline__ f32x4 mfma16(bf16x8 a, bf16x8 b, f32x4 c) {
    return __builtin_amdgcn_mfma_f32_16x16x32_bf16(a, b, c, 0, 0, 0);
}
__device__ __forceinline__ bf16x8 ldg8(const uint16_t* p) {
    return __builtin_bit_cast(bf16x8, *(const u16x8*)p);
}
__device__ __forceinline__ bf16x8 lds8(const void* base, int byteoff) {
    return __builtin_bit_cast(bf16x8, *(const u16x8*)((const char*)base + byteoff));
}

// -------- fused preprocessing: cast hs/Wq/Wk/Wv to bf16 + extract table --------
__global__ void k_cast_all(const float* __restrict__ hs, const float* __restrict__ wq,
                           const float* __restrict__ wk, const float* __restrict__ wv,
                           const float* __restrict__ rel,
                           uint16_t* __restrict__ hs_bf, uint16_t* __restrict__ w_bf,
                           uint16_t* __restrict__ tab, uint16_t* __restrict__ tabT) {
    int b = blockIdx.x;
    if (b >= 3584) {  // table extraction: 64 blocks
        int idx = (b - 3584) * 256 + threadIdx.x;
        int j = idx >> 6, d = idx & 63;
        float v = 0.0f;
        if (j < 255) v = rel[((size_t)512 * 1024 + (512 + j - 127)) * 64 + d];
        uint16_t h = f2bf(v);
        tab[j * 64 + d] = h;       // [256][64]
        tabT[d * 256 + j] = h;     // [64][256]
        return;
    }
    const float* src;
    uint16_t* dst;
    int i;
    if (b < 2048)      { src = hs; dst = hs_bf;           i = b * 256 + threadIdx.x; }
    else if (b < 2560) { src = wq; dst = w_bf;            i = (b - 2048) * 256 + threadIdx.x; }
    else if (b < 3072) { src = wk; dst = w_bf + 1048576;  i = (b - 2560) * 256 + threadIdx.x; }
    else               { src = wv; dst = w_bf + 2097152;  i = (b - 3072) * 256 + threadIdx.x; }
    float4 a = ((const float4*)src)[2 * i];
    float4 c = ((const float4*)src)[2 * i + 1];
    u16x8 o;
    o[0] = f2bf(a.x); o[1] = f2bf(a.y); o[2] = f2bf(a.z); o[3] = f2bf(a.w);
    o[4] = f2bf(c.x); o[5] = f2bf(c.y); o[6] = f2bf(c.z); o[7] = f2bf(c.w);
    ((u16x8*)dst)[i] = o;
}

// ------- fused QKV GEMM, LDS-bounced coalesced epilogue; V pre-transposed -------
// Block swizzle: each XCD owns a contiguous 4-m-block slab (1MB A, L2-resident).
__launch_bounds__(256)
__global__ void k_gemm_qkv3(const uint16_t* __restrict__ A, const uint16_t* __restrict__ Wt,
                            const float* __restrict__ bq, const float* __restrict__ bk,
                            const float* __restrict__ bvp, uint16_t* __restrict__ qout,
                            uint16_t* __restrict__ kout, uint16_t* __restrict__ vt) {
    __shared__ uint16_t Sh[2 * 128 * 64];  // As = Sh, Bs = Sh+8192; epilogue: 32KB bounce
    uint16_t* As = Sh;
    uint16_t* Bs = Sh + 8192;
    int bid = blockIdx.x;
    int xcd = bid & 7, idx = bid >> 3;          // 768 = 8 * 96
    int m0 = (xcd * 4 + (idx & 3)) * 128;       // 4 m-blocks per XCD (A-slab 1MB)
    int n0 = (idx >> 2) * 128;                  // 24 n-blocks
    int tid = threadIdx.x;
    int w = tid >> 6, l = tid & 63, lg = l >> 4, ln = l & 15;
    int wm = w >> 1, wn = w & 1;
    int lrow = tid >> 3, lcol = (tid & 7) * 8;
    f32x4 acc[4][4] = {};
    for (int kt = 0; kt < 16; ++kt) {
        int k0 = kt * 64;
        __syncthreads();
#pragma unroll
        for (int c = 0; c < 4; ++c) {
            int row = c * 32 + lrow;
            __builtin_amdgcn_global_load_lds(
                (const __attribute__((address_space(1))) void*)(A + (size_t)(m0 + row) * 1024 + k0 + lcol),
                (__attribute__((address_space(3))) void*)&As[row * 64 + lcol], 16, 0, 0);
            __builtin_amdgcn_global_load_lds(
                (const __attribute__((address_space(1))) void*)(Wt + (size_t)(n0 + row) * 1024 + k0 + lcol),
                (__attribute__((address_space(3))) void*)&Bs[row * 64 + lcol], 16, 0, 0);
        }
        __syncthreads();
#pragma unroll
        for (int ks = 0; ks < 2; ++ks) {
            bf16x8 af[4], bfr[4];
#pragma unroll
            for (int mi = 0; mi < 4; ++mi)
                af[mi] = ldg8(&As[(wm * 64 + mi * 16 + ln) * 64 + ks * 32 + lg * 8]);
#pragma unroll
            for (int ni = 0; ni < 4; ++ni)
                bfr[ni] = ldg8(&Bs[(wn * 64 + ni * 16 + ln) * 64 + ks * 32 + lg * 8]);
#pragma unroll
            for (int mi = 0; mi < 4; ++mi)
#pragma unroll
                for (int ni = 0; ni < 4; ++ni)
                    acc[mi][ni] = mfma16(af[mi], bfr[ni], acc[mi][ni]);
        }
    }
    int b = m0 >> 10, s0r = m0 & 1023;
    int which = n0 >> 10, nbase = n0 & 1023;  // uniform per block
    __syncthreads();  // all MFMA reads of Sh done; reuse as bounce buffer
    if (which < 2) {
        uint16_t* qk = which == 0 ? qout : kout;
        const float* bp = which == 0 ? bq : bk;
        // T[s2][d2] scalar writes (XOR by s2>>2 spreads lg groups)
#pragma unroll
        for (int ni = 0; ni < 4; ++ni) {
            int d2 = wn * 64 + ni * 16 + ln;
            float bb = bp[nbase + d2];
#pragma unroll
            for (int mi = 0; mi < 4; ++mi)
#pragma unroll
                for (int r = 0; r < 4; ++r) {
                    int s2 = wm * 64 + mi * 16 + lg * 4 + r;
                    *(uint16_t*)((char*)Sh + ((s2 * 256 + d2 * 2) ^ (((s2 >> 2) & 7) << 4))) =
                        f2bf(acc[mi][ni][r] + bb);
                }
        }
        __syncthreads();
        // coalesced: 8 lanes cover one (bh,s)-row's 64 d (128B contiguous)
#pragma unroll
        for (int hh = 0; hh < 2; ++hh) {
            int h = (nbase >> 6) + hh;
#pragma unroll
            for (int i = 0; i < 4; ++i) {
                int s2 = i * 32 + w * 8 + (l >> 3);
                int d2 = hh * 64 + (l & 7) * 8;
                u16x8 vv = *(u16x8*)((char*)Sh + ((s2 * 256 + d2 * 2) ^ (((s2 >> 2) & 7) << 4)));
                *(u16x8*)&qk[(((size_t)(b * 16 + h)) * 1024 + s0r + s2) * 64 + (d2 & 63)] = vv;
            }
        }
    } else {
        // T[d2][s2] u16x4 writes (XOR by d2&7)
#pragma unroll
        for (int ni = 0; ni < 4; ++ni) {
            int d2 = wn * 64 + ni * 16 + ln;
            float bb = bvp[nbase + d2];
#pragma unroll
            for (int mi = 0; mi < 4; ++mi) {
                int s2 = wm * 64 + mi * 16 + lg * 4;
                u16x4 pv;
#pragma unroll
                for (int r = 0; r < 4; ++r) pv[r] = f2bf(acc[mi][ni][r] + bb);
                *(u16x4*)((char*)Sh + ((d2 * 256 + s2 * 2) ^ ((d2 & 7) << 4))) = pv;
            }
        }
        __syncthreads();
        // coalesced: 16 lanes cover one (bh,d)-row's 128 s (256B contiguous)
#pragma unroll
        for (int i = 0; i < 8; ++i) {
            int d2 = i * 16 + w * 4 + (l >> 4);
            int s2 = (l & 15) * 8;
            u16x8 vv = *(u16x8*)((char*)Sh + ((d2 * 256 + s2 * 2) ^ ((d2 & 7) << 4)));
            int nr = nbase + d2;
            int h = nr >> 6, d = nr & 63;
            *(u16x8*)&vt[(((size_t)(b * 16 + h)) * 64 + d) * 1024 + s0r + s2] = vv;
        }
    }
}

// ---------------- R = Q @ table^T : [65536,64] @ [64,256] -> bf16 ----------
// LDS-bounce epilogue: store contiguous 512B row segments (u16x8 coalesced).
__launch_bounds__(256)
__global__ void k_r_gemm(const uint16_t* __restrict__ q, const uint16_t* __restrict__ tab,
                         uint16_t* __restrict__ R) {
    __shared__ uint16_t Qs[64 * 72];     //  9216 B
    __shared__ uint16_t Rbb[64 * 264];   // 33792 B bounce (pad 256->264)
    int m0 = blockIdx.x * 64;
    int tid = threadIdx.x;
    int w = tid >> 6, l = tid & 63, lg = l >> 4, ln = l & 15;
#pragma unroll
    for (int c = 0; c < 2; ++c) {
        int idx = c * 256 + tid; int row = idx >> 3, seg = idx & 7;
        *(u16x8*)&Qs[row * 72 + seg * 8] =
            *(const u16x8*)(q + (size_t)(m0 + row) * 64 + seg * 8);
    }
    __syncthreads();
    bf16x8 aq[4][2];
#pragma unroll
    for (int mi = 0; mi < 4; ++mi)
#pragma unroll
        for (int ks = 0; ks < 2; ++ks)
            aq[mi][ks] = ldg8(&Qs[(mi * 16 + ln) * 72 + ks * 32 + lg * 8]);
    f32x4 acc[4][4] = {};
#pragma unroll
    for (int ni = 0; ni < 4; ++ni) {
        int j = w * 64 + ni * 16 + ln;
#pragma unroll
        for (int ks = 0; ks < 2; ++ks) {
            bf16x8 bt = ldg8(tab + j * 64 + ks * 32 + lg * 8);
#pragma unroll
            for (int mi = 0; mi < 4; ++mi)
                acc[mi][ni] = mfma16(aq[mi][ks], bt, acc[mi][ni]);
        }
    }
    // bounce: Rbb[row][j], row = mi*16+lg*4+r, j = w*64+ni*16+ln
#pragma unroll
    for (int ni = 0; ni < 4; ++ni)
#pragma unroll
        for (int mi = 0; mi < 4; ++mi)
#pragma unroll
            for (int r = 0; r < 4; ++r)
                Rbb[(mi * 16 + lg * 4 + r) * 264 + w * 64 + ni * 16 + ln] =
                    f2bf(acc[mi][ni][r]);
    __syncthreads();
    // coalesced store: each row is 512B contiguous in R; 2048 16B-chunks, 8 iters
#pragma unroll
    for (int it = 0; it < 8; ++it) {
        int idx = it * 256 + tid;
        int row = idx >> 5, c = idx & 31;
        u16x8 vv = *(u16x8*)&Rbb[row * 264 + c * 8];
        *(u16x8*)&R[(size_t)(m0 + row) * 256 + c * 8] = vv;
    }
}

// ---- per-group softmax (NO-MAX, exp2): rel add (wave-uniform cls),
//      P = exp2((s+rel)*K2E), Pagg scatter, pack P into canonical PV A-frags ----
__device__ __forceinline__ void softmax_grp(
    const f32x4 (&acc)[4], int kt, int qbase, int ln, const uint16_t* __restrict__ Rrow,
    float rel_lo2, float rel_hi2, uint16_t* prow, int lg,
    float& lloc, float& slo, float& shi, uint32_t (&pk)[4][2]) {
    int cls = (kt * 64 - (qbase + 15) >= 127) ? 2
            : ((kt * 64 + 63 - qbase <= -127) ? 0 : 1);
    int qg = qbase + ln;
    float sv[16];
    if (cls == 2) {
#pragma unroll
        for (int m = 0; m < 4; ++m)
#pragma unroll
            for (int r = 0; r < 4; ++r) sv[m * 4 + r] = fmaf(acc[m][r], K2E, rel_hi2);
    } else if (cls == 0) {
#pragma unroll
        for (int m = 0; m < 4; ++m)
#pragma unroll
            for (int r = 0; r < 4; ++r) sv[m * 4 + r] = fmaf(acc[m][r], K2E, rel_lo2);
    } else {
#pragma unroll
        for (int m = 0; m < 4; ++m) {
            int base = kt * 64 + (m >> 1) * 32 + lg * 8 + (m & 1) * 4 - qg;  // k(m,r)-qg
#pragma unroll
            for (int r = 0; r < 4; ++r) {
                int dj = base + r;
                int djc = dj < -127 ? -127 : (dj > 127 ? 127 : dj);
                float rel = bf2f(Rrow[djc + 127]);  // global, L2-hot
                sv[m * 4 + r] = (acc[m][r] + rel) * K2E;
            }
        }
    }
    float pm[4];
    if (cls == 1) {
#pragma unroll
        for (int m = 0; m < 4; ++m) {
            int base = kt * 64 + (m >> 1) * 32 + lg * 8 + (m & 1) * 4 - qg;
            uint32_t w0 = 0, w1 = 0;
            float ps = 0.f;
#pragma unroll
            for (int r = 0; r < 4; ++r) {
                float P = hw_exp2(sv[m * 4 + r]);
                ps += P;
                uint32_t h = f2bf_rn(P);
                int dj = base + r;
                if (dj <= -127) slo += P;
                else if (dj >= 127) shi += P;
                else prow[dj + 127] = (uint16_t)h;
                if (r < 2) w0 |= h << (16 * r); else w1 |= h << (16 * (r - 2));
            }
            pm[m] = ps;
            pk[m][0] = w0; pk[m][1] = w1;
        }
    } else {
#pragma unroll
        for (int m = 0; m < 4; ++m) {
            uint32_t w0 = 0, w1 = 0;
            float ps = 0.f;
#pragma unroll
            for (int r = 0; r < 4; ++r) {
                float P = hw_exp2(sv[m * 4 + r]);
                ps += P;
                uint32_t h = f2bf_rn(P);
                if (r < 2) w0 |= h << (16 * r); else w1 |= h << (16 * (r - 2));
            }
            pm[m] = ps;
            pk[m][0] = w0; pk[m][1] = w1;
        }
        float ts = (pm[0] + pm[1]) + (pm[2] + pm[3]);
        if (cls == 2) shi += ts; else slo += ts;
    }
    lloc += (pm[0] + pm[1]) + (pm[2] + pm[3]);  // 4-way partials -> short chain
}

// ---------------- fused attention: QBLK=128, 2 q-groups per wave ----------------
// (R9 structure: K+V staged each tile, reg-prefetch next tile, 2 barriers/tile)
__launch_bounds__(256, 2)
__global__ void k_attn_fused(const uint16_t* __restrict__ qb, const uint16_t* __restrict__ kb,
                             const uint16_t* __restrict__ vtb, const uint16_t* __restrict__ Rb,
                             const uint16_t* __restrict__ tabT, float* __restrict__ out) {
    __shared__ uint16_t Pagg[128 * 256];  // 65536 B, rows wave-private
    __shared__ uint16_t Kb[64 * 64];      //  8192 B, slotK-swizzled [k][d]
    __shared__ uint16_t Vb[64 * 64];      //  8192 B, (row&7)-swizzled V^T [d][k]
    int bid = blockIdx.x;
    bid = (bid & 7) * 64 + (bid >> 3);    // XCD-bijective swizzle (512 wgs)
    int bh = bid >> 3, q0 = (bid & 7) * 128;
    int tid = threadIdx.x;
    int w = tid >> 6, l = tid & 63, lg = l >> 4, ln = l & 15;
    int qbaseA = q0 + w * 16, qbaseB = qbaseA + 64;
    int qA = qbaseA + ln, qB = qA + 64;   // this lane's two softmax q-rows
    bf16x8 qfA[2], qfB[2];
    {
        const uint16_t* qr = qb + ((size_t)bh * 1024 + qA) * 64;
        qfA[0] = ldg8(qr + lg * 8); qfA[1] = ldg8(qr + 32 + lg * 8);
        qr += 64 * 64;
        qfB[0] = ldg8(qr + lg * 8); qfB[1] = ldg8(qr + 32 + lg * 8);
    }
    const uint16_t* RrowA = Rb + ((size_t)bh * 1024 + qA) * 256;
    const uint16_t* RrowB = RrowA + 64 * 256;
    uint16_t* prowA = &Pagg[(w * 16 + ln) * 256];
    uint16_t* prowB = &Pagg[(64 + w * 16 + ln) * 256];
    {   // zero this wave's 32 Pagg rows (wave-private -> no barrier)
        u16x8* pa = (u16x8*)&Pagg[(w * 16) * 256];
        u16x8* pb2 = (u16x8*)&Pagg[(64 + w * 16) * 256];
#pragma unroll
        for (int i = 0; i < 8; ++i) { pa[i * 64 + l] = (u16x8)0; pb2[i * 64 + l] = (u16x8)0; }
    }
    float relA_lo = bf2f(RrowA[0]) * K2E, relA_hi = bf2f(RrowA[254]) * K2E;
    float relB_lo = bf2f(RrowB[0]) * K2E, relB_hi = bf2f(RrowB[254]) * K2E;
    // staging geometry (16B chunks; rows 0..31 chunk0, 32..63 chunk1)
    const int r0 = tid >> 3, c16 = tid & 7;
    const int r1 = 32 + r0;
    const int slotK0 = (r0 & 3) | ((r0 >> 1) & 4), slotK1 = (r1 & 3) | ((r1 >> 1) & 4);
    const int waK0 = (r0 * 128 + c16 * 16) ^ (slotK0 << 4);
    const int waK1 = (r1 * 128 + c16 * 16) ^ (slotK1 << 4);
    const int waV0 = (r0 * 128 + c16 * 16) ^ ((r0 & 7) << 4);
    const int waV1 = (r1 * 128 + c16 * 16) ^ ((r1 & 7) << 4);
    const uint16_t* kt_base = kb + ((size_t)bh * 1024) * 64;
    const uint16_t* vt_base = vtb + (size_t)bh * 64 * 1024;
    // prefetch tile 0
    u16x8 kc0 = *(const u16x8*)(kt_base + (size_t)r0 * 64 + c16 * 8);
    u16x8 kc1 = *(const u16x8*)(kt_base + (size_t)r1 * 64 + c16 * 8);
    u16x8 vc0 = *(const u16x8*)(vt_base + (size_t)r0 * 1024 + c16 * 8);
    u16x8 vc1 = *(const u16x8*)(vt_base + (size_t)r1 * 1024 + c16 * 8);
    float llocA = 0.f, sloA = 0.f, shiA = 0.f;
    float llocB = 0.f, sloB = 0.f, shiB = 0.f;
    f32x4 oaccA[4] = {}, oaccB[4] = {};
    for (int kt = 0; kt < 16; ++kt) {
        __syncthreads();  // previous tile's LDS reads complete
        *(u16x8*)((char*)Kb + waK0) = kc0;
        *(u16x8*)((char*)Kb + waK1) = kc1;
        *(u16x8*)((char*)Vb + waV0) = vc0;
        *(u16x8*)((char*)Vb + waV1) = vc1;
        __syncthreads();  // tile kt visible
        if (kt < 15) {    // prefetch kt+1; latency hides under compute
            const uint16_t* kn = kt_base + (size_t)(kt + 1) * 64 * 64;
            const uint16_t* vn = vt_base + (kt + 1) * 64;
            kc0 = *(const u16x8*)(kn + (size_t)r0 * 64 + c16 * 8);
            kc1 = *(const u16x8*)(kn + (size_t)r1 * 64 + c16 * 8);
            vc0 = *(const u16x8*)(vn + (size_t)r0 * 1024 + c16 * 8);
            vc1 = *(const u16x8*)(vn + (size_t)r1 * 1024 + c16 * 8);
        }
        // QK^T with pi-permuted k-rows; each K-fragment feeds BOTH q-groups
        f32x4 accA[4] = {}, accB[4] = {};
        __builtin_amdgcn_s_setprio(1);
#pragma unroll
        for (int m = 0; m < 4; ++m) {
            int rowp = ((m >> 1) << 5) + ((ln >> 2) << 3) + ((m & 1) << 2) + (ln & 3);
            // slotK(rowp) == ln&7 -> uniform bank pattern
            bf16x8 a0 = lds8(Kb, (rowp * 128 + lg * 16) ^ ((ln & 7) << 4));
            bf16x8 a1 = lds8(Kb, (rowp * 128 + 64 + lg * 16) ^ ((ln & 7) << 4));
            accA[m] = mfma16(a0, qfA[0], accA[m]);
            accA[m] = mfma16(a1, qfA[1], accA[m]);
            accB[m] = mfma16(a0, qfB[0], accB[m]);
            accB[m] = mfma16(a1, qfB[1], accB[m]);
        }
        __builtin_amdgcn_s_setprio(0);
        uint32_t pkA[4][2], pkB[4][2];
        softmax_grp(accA, kt, qbaseA, ln, RrowA, relA_lo, relA_hi, prowA, lg,
                    llocA, sloA, shiA, pkA);
        softmax_grp(accB, kt, qbaseB, ln, RrowB, relB_lo, relB_hi, prowB, lg,
                    llocB, sloB, shiB, pkB);
        // O += P @ V: A-fragments are register renames of pk (canonical layout)
        __builtin_amdgcn_s_setprio(1);
#pragma unroll
        for (int ks = 0; ks < 2; ++ks) {
            uint32_t fa[4] = {pkA[2 * ks][0], pkA[2 * ks][1], pkA[2 * ks + 1][0], pkA[2 * ks + 1][1]};
            uint32_t fb[4] = {pkB[2 * ks][0], pkB[2 * ks][1], pkB[2 * ks + 1][0], pkB[2 * ks + 1][1]};
            bf16x8 apA = __builtin_bit_cast(bf16x8, fa);
            bf16x8 apB = __builtin_bit_cast(bf16x8, fb);
#pragma unroll
            for (int nt = 0; nt < 4; ++nt) {
                int row = nt * 16 + ln;
                bf16x8 bv = lds8(Vb, (row * 128 + (ks * 4 + lg) * 16) ^ ((ln & 7) << 4));
                oaccA[nt] = mfma16(apA, bv, oaccA[nt]);
                oaccB[nt] = mfma16(apB, bv, oaccB[nt]);
            }
        }
        __builtin_amdgcn_s_setprio(0);
    }
    llocA += __shfl_xor(llocA, 16); llocA += __shfl_xor(llocA, 32);
    sloA  += __shfl_xor(sloA, 16);  sloA  += __shfl_xor(sloA, 32);
    shiA  += __shfl_xor(shiA, 16);  shiA  += __shfl_xor(shiA, 32);
    llocB += __shfl_xor(llocB, 16); llocB += __shfl_xor(llocB, 32);
    sloB  += __shfl_xor(sloB, 16);  sloB  += __shfl_xor(sloB, 32);
    shiB  += __shfl_xor(shiB, 16);  shiB  += __shfl_xor(shiB, 32);
    if (lg == 0) {
        prowA[0] = f2bf(sloA); prowA[254] = f2bf(shiA);
        prowB[0] = f2bf(sloB); prowB[254] = f2bf(shiB);
    }
    // O += Pagg @ table (B^T = tabT[d][j]); bt shared by both groups
#pragma unroll
    for (int ks8 = 0; ks8 < 8; ++ks8) {
        bf16x8 apA = ldg8(&Pagg[(w * 16 + ln) * 256 + ks8 * 32 + lg * 8]);
        bf16x8 apB = ldg8(&Pagg[(64 + w * 16 + ln) * 256 + ks8 * 32 + lg * 8]);
#pragma unroll
        for (int nt = 0; nt < 4; ++nt) {
            bf16x8 bt = ldg8(tabT + (size_t)(nt * 16 + ln) * 256 + ks8 * 32 + lg * 8);
            oaccA[nt] = mfma16(apA, bt, oaccA[nt]);
            oaccB[nt] = mfma16(apB, bt, oaccB[nt]);
        }
    }
    float rinvA[4], rinvB[4];
#pragma unroll
    for (int r = 0; r < 4; ++r) {
        rinvA[r] = 1.0f / __shfl(llocA, lg * 4 + r);
        rinvB[r] = 1.0f / __shfl(llocB, lg * 4 + r);
    }
    int b = bh >> 4, h = bh & 15;
#pragma unroll
    for (int nt = 0; nt < 4; ++nt) {
#pragma unroll
        for (int r = 0; r < 4; ++r) {
            int qoA = q0 + w * 16 + lg * 4 + r;
            out[((size_t)b * 1024 + qoA) * 1024 + h * 64 + nt * 16 + ln] = oaccA[nt][r] * rinvA[r];
            out[((size_t)b * 1024 + qoA + 64) * 1024 + h * 64 + nt * 16 + ln] = oaccB[nt][r] * rinvB[r];
        }
    }
}

extern "C" void kernel_launch(void* const* d_in, const int* in_sizes, int n_in,
                              void* d_out, int out_size, void* d_ws, size_t ws_size,
                              hipStream_t stream) {
    const float* hs  = (const float*)d_in[0];
    const float* Wq  = (const float*)d_in[1];
    const float* bq  = (const float*)d_in[2];
    const float* Wk  = (const float*)d_in[3];
    const float* bk  = (const float*)d_in[4];
    const float* Wv  = (const float*)d_in[5];
    const float* bv  = (const float*)d_in[6];
    const float* rel = (const float*)d_in[7];
    float* out = (float*)d_out;
    char* ws = (char*)d_ws;

    uint16_t* hs_bf = (uint16_t*)(ws);                // 8 MB   [4096][1024]
    uint16_t* W_bf  = (uint16_t*)(ws + 8388608);      // 6 MB   [3072][1024]
    uint16_t* q_bf  = (uint16_t*)(ws + 14680064);     // 8 MB   [64][1024][64]
    uint16_t* k_bf  = (uint16_t*)(ws + 23068672);     // 8 MB   [64][1024][64]
    uint16_t* vt_bf = (uint16_t*)(ws + 31457280);     // 8 MB   [64][64][1024]
    uint16_t* R_bf  = (uint16_t*)(ws + 48234496);     // 32 MB  [65536][256]
    uint16_t* tab   = (uint16_t*)(ws + 81788928);     // 32 KB  [256][64]
    uint16_t* tabT  = (uint16_t*)(ws + 81821696);     // 32 KB  [64][256]

    k_cast_all<<<3648, 256, 0, stream>>>(hs, Wq, Wk, Wv, rel, hs_bf, W_bf, tab, tabT);

    k_gemm_qkv3<<<768, 256, 0, stream>>>(hs_bf, W_bf, bq, bk, bv, q_bf, k_bf, vt_bf);
    k_r_gemm<<<1024, 256, 0, stream>>>(q_bf, tab, R_bf);

    k_attn_fused<<<512, 256, 0, stream>>>(q_bf, k_bf, vt_bf, R_bf, tabT, out);
}

// Round 18
// 126.149 us; speedup vs baseline: 1.0296x; 1.0126x over previous
//
#include <hip/hip_runtime.h>
#include <stdint.h>

// NeZha self-attention, B=4 S=1024 H=1024 NH=16 HD=64 MAX_REL=127.
// rel_pos[q,k,:] == table[clip(k-q,-127,127)+127,:], table is 255x64.
//  - score rel term:  gather from R = Q @ table^T (computed in attn PROLOGUE:
//    each block owns its 128 R-rows exclusively -> fused, no separate dispatch)
//  - ctx rel term:    Pagg @ table (banded prob aggregation; clipped tails in regs)
// v18: R17 (=R15 session best) + k_r_gemm FUSED into attn prologue: each wave
//      computes R for its own 32 q-rows (qfA/qfB are exactly r_gemm's
//      A-fragments), stores to its block-owned R_bf slice, vmcnt(0) drain,
//      then the k-loop gathers as before. Eliminates 1 dispatch + dup q read.

typedef __bf16 bf16x8 __attribute__((ext_vector_type(8)));
typedef float f32x4 __attribute__((ext_vector_type(4)));
typedef uint16_t u16x8 __attribute__((ext_vector_type(8)));
typedef uint16_t u16x4 __attribute__((ext_vector_type(4)));

#define K2E 0.18033688011112042f  // 0.125 * log2(e)

__device__ __forceinline__ float hw_exp2(float x) {
    return __builtin_amdgcn_exp2f(x);  // bare v_exp_f32
}
__device__ __forceinline__ uint16_t f2bf(float f) {
    uint32_t u = __builtin_bit_cast(uint32_t, f);
    return (uint16_t)((u + 0x7FFFu + ((u >> 16) & 1u)) >> 16);
}
__device__ __forceinline__ uint16_t f2bf_rn(float f) {  // hw cvt, RNE
    return __builtin_bit_cast(uint16_t, (__bf16)f);
}
__device__ __forceinline__ float bf2f(uint16_t h) {
    uint32_t u = ((uint32_t)h) << 16;
    return __builtin_bit_cast(float, u);
}
__device__ __forceinline__ f32x4 mfma16(bf16x8 a, bf16x8 b, f32x4 c) {
    return __builtin_amdgcn_mfma_f32_16x16x32_bf16(a, b, c, 0, 0, 0);
}
__device__ __forceinline__ bf16x8 ldg8(const uint16_t* p) {
    return __builtin_bit_cast(bf16x8, *(const u16x8*)p);
}
__device__ __forceinline__ bf16x8 lds8(const void* base, int byteoff) {
    return __builtin_bit_cast(bf16x8, *(const u16x8*)((const char*)base + byteoff));
}

// -------- fused preprocessing: cast hs/Wq/Wk/Wv to bf16 + extract table --------
__global__ void k_cast_all(const float* __restrict__ hs, const float* __restrict__ wq,
                           const float* __restrict__ wk, const float* __restrict__ wv,
                           const float* __restrict__ rel,
                           uint16_t* __restrict__ hs_bf, uint16_t* __restrict__ w_bf,
                           uint16_t* __restrict__ tab, uint16_t* __restrict__ tabT) {
    int b = blockIdx.x;
    if (b >= 3584) {  // table extraction: 64 blocks
        int idx = (b - 3584) * 256 + threadIdx.x;
        int j = idx >> 6, d = idx & 63;
        float v = 0.0f;
        if (j < 255) v = rel[((size_t)512 * 1024 + (512 + j - 127)) * 64 + d];
        uint16_t h = f2bf(v);
        tab[j * 64 + d] = h;       // [256][64]
        tabT[d * 256 + j] = h;     // [64][256]
        return;
    }
    const float* src;
    uint16_t* dst;
    int i;
    if (b < 2048)      { src = hs; dst = hs_bf;           i = b * 256 + threadIdx.x; }
    else if (b < 2560) { src = wq; dst = w_bf;            i = (b - 2048) * 256 + threadIdx.x; }
    else if (b < 3072) { src = wk; dst = w_bf + 1048576;  i = (b - 2560) * 256 + threadIdx.x; }
    else               { src = wv; dst = w_bf + 2097152;  i = (b - 3072) * 256 + threadIdx.x; }
    float4 a = ((const float4*)src)[2 * i];
    float4 c = ((const float4*)src)[2 * i + 1];
    u16x8 o;
    o[0] = f2bf(a.x); o[1] = f2bf(a.y); o[2] = f2bf(a.z); o[3] = f2bf(a.w);
    o[4] = f2bf(c.x); o[5] = f2bf(c.y); o[6] = f2bf(c.z); o[7] = f2bf(c.w);
    ((u16x8*)dst)[i] = o;
}

// ------- fused QKV GEMM, LDS-bounced coalesced epilogue; V pre-transposed -------
// Block swizzle: each XCD owns a contiguous 4-m-block slab (1MB A, L2-resident).
__launch_bounds__(256)
__global__ void k_gemm_qkv3(const uint16_t* __restrict__ A, const uint16_t* __restrict__ Wt,
                            const float* __restrict__ bq, const float* __restrict__ bk,
                            const float* __restrict__ bvp, uint16_t* __restrict__ qout,
                            uint16_t* __restrict__ kout, uint16_t* __restrict__ vt) {
    __shared__ uint16_t Sh[2 * 128 * 64];  // As = Sh, Bs = Sh+8192; epilogue: 32KB bounce
    uint16_t* As = Sh;
    uint16_t* Bs = Sh + 8192;
    int bid = blockIdx.x;
    int xcd = bid & 7, idx = bid >> 3;          // 768 = 8 * 96
    int m0 = (xcd * 4 + (idx & 3)) * 128;       // 4 m-blocks per XCD (A-slab 1MB)
    int n0 = (idx >> 2) * 128;                  // 24 n-blocks
    int tid = threadIdx.x;
    int w = tid >> 6, l = tid & 63, lg = l >> 4, ln = l & 15;
    int wm = w >> 1, wn = w & 1;
    int lrow = tid >> 3, lcol = (tid & 7) * 8;
    f32x4 acc[4][4] = {};
    for (int kt = 0; kt < 16; ++kt) {
        int k0 = kt * 64;
        __syncthreads();
#pragma unroll
        for (int c = 0; c < 4; ++c) {
            int row = c * 32 + lrow;
            __builtin_amdgcn_global_load_lds(
                (const __attribute__((address_space(1))) void*)(A + (size_t)(m0 + row) * 1024 + k0 + lcol),
                (__attribute__((address_space(3))) void*)&As[row * 64 + lcol], 16, 0, 0);
            __builtin_amdgcn_global_load_lds(
                (const __attribute__((address_space(1))) void*)(Wt + (size_t)(n0 + row) * 1024 + k0 + lcol),
                (__attribute__((address_space(3))) void*)&Bs[row * 64 + lcol], 16, 0, 0);
        }
        __syncthreads();
#pragma unroll
        for (int ks = 0; ks < 2; ++ks) {
            bf16x8 af[4], bfr[4];
#pragma unroll
            for (int mi = 0; mi < 4; ++mi)
                af[mi] = ldg8(&As[(wm * 64 + mi * 16 + ln) * 64 + ks * 32 + lg * 8]);
#pragma unroll
            for (int ni = 0; ni < 4; ++ni)
                bfr[ni] = ldg8(&Bs[(wn * 64 + ni * 16 + ln) * 64 + ks * 32 + lg * 8]);
#pragma unroll
            for (int mi = 0; mi < 4; ++mi)
#pragma unroll
                for (int ni = 0; ni < 4; ++ni)
                    acc[mi][ni] = mfma16(af[mi], bfr[ni], acc[mi][ni]);
        }
    }
    int b = m0 >> 10, s0r = m0 & 1023;
    int which = n0 >> 10, nbase = n0 & 1023;  // uniform per block
    __syncthreads();  // all MFMA reads of Sh done; reuse as bounce buffer
    if (which < 2) {
        uint16_t* qk = which == 0 ? qout : kout;
        const float* bp = which == 0 ? bq : bk;
        // T[s2][d2] scalar writes (XOR by s2>>2 spreads lg groups)
#pragma unroll
        for (int ni = 0; ni < 4; ++ni) {
            int d2 = wn * 64 + ni * 16 + ln;
            float bb = bp[nbase + d2];
#pragma unroll
            for (int mi = 0; mi < 4; ++mi)
#pragma unroll
                for (int r = 0; r < 4; ++r) {
                    int s2 = wm * 64 + mi * 16 + lg * 4 + r;
                    *(uint16_t*)((char*)Sh + ((s2 * 256 + d2 * 2) ^ (((s2 >> 2) & 7) << 4))) =
                        f2bf(acc[mi][ni][r] + bb);
                }
        }
        __syncthreads();
        // coalesced: 8 lanes cover one (bh,s)-row's 64 d (128B contiguous)
#pragma unroll
        for (int hh = 0; hh < 2; ++hh) {
            int h = (nbase >> 6) + hh;
#pragma unroll
            for (int i = 0; i < 4; ++i) {
                int s2 = i * 32 + w * 8 + (l >> 3);
                int d2 = hh * 64 + (l & 7) * 8;
                u16x8 vv = *(u16x8*)((char*)Sh + ((s2 * 256 + d2 * 2) ^ (((s2 >> 2) & 7) << 4)));
                *(u16x8*)&qk[(((size_t)(b * 16 + h)) * 1024 + s0r + s2) * 64 + (d2 & 63)] = vv;
            }
        }
    } else {
        // T[d2][s2] u16x4 writes (XOR by d2&7)
#pragma unroll
        for (int ni = 0; ni < 4; ++ni) {
            int d2 = wn * 64 + ni * 16 + ln;
            float bb = bvp[nbase + d2];
#pragma unroll
            for (int mi = 0; mi < 4; ++mi) {
                int s2 = wm * 64 + mi * 16 + lg * 4;
                u16x4 pv;
#pragma unroll
                for (int r = 0; r < 4; ++r) pv[r] = f2bf(acc[mi][ni][r] + bb);
                *(u16x4*)((char*)Sh + ((d2 * 256 + s2 * 2) ^ ((d2 & 7) << 4))) = pv;
            }
        }
        __syncthreads();
        // coalesced: 16 lanes cover one (bh,d)-row's 128 s (256B contiguous)
#pragma unroll
        for (int i = 0; i < 8; ++i) {
            int d2 = i * 16 + w * 4 + (l >> 4);
            int s2 = (l & 15) * 8;
            u16x8 vv = *(u16x8*)((char*)Sh + ((d2 * 256 + s2 * 2) ^ ((d2 & 7) << 4)));
            int nr = nbase + d2;
            int h = nr >> 6, d = nr & 63;
            *(u16x8*)&vt[(((size_t)(b * 16 + h)) * 64 + d) * 1024 + s0r + s2] = vv;
        }
    }
}

// ---- per-group softmax (NO-MAX, exp2): rel add (wave-uniform cls),
//      P = exp2((s+rel)*K2E), Pagg scatter, pack P into canonical PV A-frags ----
__device__ __forceinline__ void softmax_grp(
    const f32x4 (&acc)[4], int kt, int qbase, int ln, const uint16_t* __restrict__ Rrow,
    float rel_lo2, float rel_hi2, uint16_t* prow, int lg,
    float& lloc, float& slo, float& shi, uint32_t (&pk)[4][2]) {
    int cls = (kt * 64 - (qbase + 15) >= 127) ? 2
            : ((kt * 64 + 63 - qbase <= -127) ? 0 : 1);
    int qg = qbase + ln;
    float sv[16];
    if (cls == 2) {
#pragma unroll
        for (int m = 0; m < 4; ++m)
#pragma unroll
            for (int r = 0; r < 4; ++r) sv[m * 4 + r] = fmaf(acc[m][r], K2E, rel_hi2);
    } else if (cls == 0) {
#pragma unroll
        for (int m = 0; m < 4; ++m)
#pragma unroll
            for (int r = 0; r < 4; ++r) sv[m * 4 + r] = fmaf(acc[m][r], K2E, rel_lo2);
    } else {
#pragma unroll
        for (int m = 0; m < 4; ++m) {
            int base = kt * 64 + (m >> 1) * 32 + lg * 8 + (m & 1) * 4 - qg;  // k(m,r)-qg
#pragma unroll
            for (int r = 0; r < 4; ++r) {
                int dj = base + r;
                int djc = dj < -127 ? -127 : (dj > 127 ? 127 : dj);
                float rel = bf2f(Rrow[djc + 127]);  // global, L2-hot
                sv[m * 4 + r] = (acc[m][r] + rel) * K2E;
            }
        }
    }
    float pm[4];
    if (cls == 1) {
#pragma unroll
        for (int m = 0; m < 4; ++m) {
            int base = kt * 64 + (m >> 1) * 32 + lg * 8 + (m & 1) * 4 - qg;
            uint32_t w0 = 0, w1 = 0;
            float ps = 0.f;
#pragma unroll
            for (int r = 0; r < 4; ++r) {
                float P = hw_exp2(sv[m * 4 + r]);
                ps += P;
                uint32_t h = f2bf_rn(P);
                int dj = base + r;
                if (dj <= -127) slo += P;
                else if (dj >= 127) shi += P;
                else prow[dj + 127] = (uint16_t)h;
                if (r < 2) w0 |= h << (16 * r); else w1 |= h << (16 * (r - 2));
            }
            pm[m] = ps;
            pk[m][0] = w0; pk[m][1] = w1;
        }
    } else {
#pragma unroll
        for (int m = 0; m < 4; ++m) {
            uint32_t w0 = 0, w1 = 0;
            float ps = 0.f;
#pragma unroll
            for (int r = 0; r < 4; ++r) {
                float P = hw_exp2(sv[m * 4 + r]);
                ps += P;
                uint32_t h = f2bf_rn(P);
                if (r < 2) w0 |= h << (16 * r); else w1 |= h << (16 * (r - 2));
            }
            pm[m] = ps;
            pk[m][0] = w0; pk[m][1] = w1;
        }
        float ts = (pm[0] + pm[1]) + (pm[2] + pm[3]);
        if (cls == 2) shi += ts; else slo += ts;
    }
    lloc += (pm[0] + pm[1]) + (pm[2] + pm[3]);  // 4-way partials -> short chain
}

// ---------------- fused attention: QBLK=128, 2 q-groups per wave ----------------
// Prologue computes this block's 128 R-rows (R = Q @ table^T) into its owned
// R_bf slice; k-loop as R15 (K+V staged, reg-prefetch, 2 barriers/tile).
__launch_bounds__(256, 2)
__global__ void k_attn_fused(const uint16_t* __restrict__ qb, const uint16_t* __restrict__ kb,
                             const uint16_t* __restrict__ vtb, uint16_t* Rb,
                             const uint16_t* __restrict__ tab,
                             const uint16_t* __restrict__ tabT, float* __restrict__ out) {
    __shared__ uint16_t Pagg[128 * 256];  // 65536 B, rows wave-private
    __shared__ uint16_t Kb[64 * 64];      //  8192 B, slotK-swizzled [k][d]
    __shared__ uint16_t Vb[64 * 64];      //  8192 B, (row&7)-swizzled V^T [d][k]
    int bid = blockIdx.x;
    bid = (bid & 7) * 64 + (bid >> 3);    // XCD-bijective swizzle (512 wgs)
    int bh = bid >> 3, q0 = (bid & 7) * 128;
    int tid = threadIdx.x;
    int w = tid >> 6, l = tid & 63, lg = l >> 4, ln = l & 15;
    int qbaseA = q0 + w * 16, qbaseB = qbaseA + 64;
    int qA = qbaseA + ln, qB = qA + 64;   // this lane's two softmax q-rows
    bf16x8 qfA[2], qfB[2];
    {
        const uint16_t* qr = qb + ((size_t)bh * 1024 + qA) * 64;
        qfA[0] = ldg8(qr + lg * 8); qfA[1] = ldg8(qr + 32 + lg * 8);
        qr += 64 * 64;
        qfB[0] = ldg8(qr + lg * 8); qfB[1] = ldg8(qr + 32 + lg * 8);
    }
    {   // zero this wave's 32 Pagg rows (wave-private -> no barrier)
        u16x8* pa = (u16x8*)&Pagg[(w * 16) * 256];
        u16x8* pb2 = (u16x8*)&Pagg[(64 + w * 16) * 256];
#pragma unroll
        for (int i = 0; i < 8; ++i) { pa[i * 64 + l] = (u16x8)0; pb2[i * 64 + l] = (u16x8)0; }
    }
    // ---- fused R-GEMM: this wave's 32 R-rows (A: qbaseA+lg*4+r, B: +64) ----
    // qfA/qfB are exactly the A-fragments (row=ln, k=ks*32+lg*8); B = tab rows j.
    uint16_t* RoutA = Rb + ((size_t)bh * 1024 + qbaseA) * 256;
#pragma unroll
    for (int jt = 0; jt < 16; ++jt) {
        bf16x8 bt0 = ldg8(tab + (size_t)(jt * 16 + ln) * 64 + lg * 8);
        bf16x8 bt1 = ldg8(tab + (size_t)(jt * 16 + ln) * 64 + 32 + lg * 8);
        f32x4 ra = {}, rb2 = {};
        ra = mfma16(qfA[0], bt0, ra);  ra = mfma16(qfA[1], bt1, ra);
        rb2 = mfma16(qfB[0], bt0, rb2); rb2 = mfma16(qfB[1], bt1, rb2);
#pragma unroll
        for (int r = 0; r < 4; ++r) {
            RoutA[(size_t)(lg * 4 + r) * 256 + jt * 16 + ln] = f2bf(ra[r]);
            RoutA[(size_t)(64 + lg * 4 + r) * 256 + jt * 16 + ln] = f2bf(rb2[r]);
        }
    }
    asm volatile("s_waitcnt vmcnt(0)" ::: "memory");  // R visible to this block's gathers
    const uint16_t* RrowA = Rb + ((size_t)bh * 1024 + qA) * 256;
    const uint16_t* RrowB = RrowA + 64 * 256;
    uint16_t* prowA = &Pagg[(w * 16 + ln) * 256];
    uint16_t* prowB = &Pagg[(64 + w * 16 + ln) * 256];
    float relA_lo = bf2f(RrowA[0]) * K2E, relA_hi = bf2f(RrowA[254]) * K2E;
    float relB_lo = bf2f(RrowB[0]) * K2E, relB_hi = bf2f(RrowB[254]) * K2E;
    // staging geometry (16B chunks; rows 0..31 chunk0, 32..63 chunk1)
    const int r0 = tid >> 3, c16 = tid & 7;
    const int r1 = 32 + r0;
    const int slotK0 = (r0 & 3) | ((r0 >> 1) & 4), slotK1 = (r1 & 3) | ((r1 >> 1) & 4);
    const int waK0 = (r0 * 128 + c16 * 16) ^ (slotK0 << 4);
    const int waK1 = (r1 * 128 + c16 * 16) ^ (slotK1 << 4);
    const int waV0 = (r0 * 128 + c16 * 16) ^ ((r0 & 7) << 4);
    const int waV1 = (r1 * 128 + c16 * 16) ^ ((r1 & 7) << 4);
    const uint16_t* kt_base = kb + ((size_t)bh * 1024) * 64;
    const uint16_t* vt_base = vtb + (size_t)bh * 64 * 1024;
    // prefetch tile 0
    u16x8 kc0 = *(const u16x8*)(kt_base + (size_t)r0 * 64 + c16 * 8);
    u16x8 kc1 = *(const u16x8*)(kt_base + (size_t)r1 * 64 + c16 * 8);
    u16x8 vc0 = *(const u16x8*)(vt_base + (size_t)r0 * 1024 + c16 * 8);
    u16x8 vc1 = *(const u16x8*)(vt_base + (size_t)r1 * 1024 + c16 * 8);
    float llocA = 0.f, sloA = 0.f, shiA = 0.f;
    float llocB = 0.f, sloB = 0.f, shiB = 0.f;
    f32x4 oaccA[4] = {}, oaccB[4] = {};
    for (int kt = 0; kt < 16; ++kt) {
        __syncthreads();  // previous tile's LDS reads complete
        *(u16x8*)((char*)Kb + waK0) = kc0;
        *(u16x8*)((char*)Kb + waK1) = kc1;
        *(u16x8*)((char*)Vb + waV0) = vc0;
        *(u16x8*)((char*)Vb + waV1) = vc1;
        __syncthreads();  // tile kt visible
        if (kt < 15) {    // prefetch kt+1; latency hides under compute
            const uint16_t* kn = kt_base + (size_t)(kt + 1) * 64 * 64;
            const uint16_t* vn = vt_base + (kt + 1) * 64;
            kc0 = *(const u16x8*)(kn + (size_t)r0 * 64 + c16 * 8);
            kc1 = *(const u16x8*)(kn + (size_t)r1 * 64 + c16 * 8);
            vc0 = *(const u16x8*)(vn + (size_t)r0 * 1024 + c16 * 8);
            vc1 = *(const u16x8*)(vn + (size_t)r1 * 1024 + c16 * 8);
        }
        // QK^T with pi-permuted k-rows; each K-fragment feeds BOTH q-groups
        f32x4 accA[4] = {}, accB[4] = {};
        __builtin_amdgcn_s_setprio(1);
#pragma unroll
        for (int m = 0; m < 4; ++m) {
            int rowp = ((m >> 1) << 5) + ((ln >> 2) << 3) + ((m & 1) << 2) + (ln & 3);
            // slotK(rowp) == ln&7 -> uniform bank pattern
            bf16x8 a0 = lds8(Kb, (rowp * 128 + lg * 16) ^ ((ln & 7) << 4));
            bf16x8 a1 = lds8(Kb, (rowp * 128 + 64 + lg * 16) ^ ((ln & 7) << 4));
            accA[m] = mfma16(a0, qfA[0], accA[m]);
            accA[m] = mfma16(a1, qfA[1], accA[m]);
            accB[m] = mfma16(a0, qfB[0], accB[m]);
            accB[m] = mfma16(a1, qfB[1], accB[m]);
        }
        __builtin_amdgcn_s_setprio(0);
        uint32_t pkA[4][2], pkB[4][2];
        softmax_grp(accA, kt, qbaseA, ln, RrowA, relA_lo, relA_hi, prowA, lg,
                    llocA, sloA, shiA, pkA);
        softmax_grp(accB, kt, qbaseB, ln, RrowB, relB_lo, relB_hi, prowB, lg,
                    llocB, sloB, shiB, pkB);
        // O += P @ V: A-fragments are register renames of pk (canonical layout)
        __builtin_amdgcn_s_setprio(1);
#pragma unroll
        for (int ks = 0; ks < 2; ++ks) {
            uint32_t fa[4] = {pkA[2 * ks][0], pkA[2 * ks][1], pkA[2 * ks + 1][0], pkA[2 * ks + 1][1]};
            uint32_t fb[4] = {pkB[2 * ks][0], pkB[2 * ks][1], pkB[2 * ks + 1][0], pkB[2 * ks + 1][1]};
            bf16x8 apA = __builtin_bit_cast(bf16x8, fa);
            bf16x8 apB = __builtin_bit_cast(bf16x8, fb);
#pragma unroll
            for (int nt = 0; nt < 4; ++nt) {
                int row = nt * 16 + ln;
                bf16x8 bv = lds8(Vb, (row * 128 + (ks * 4 + lg) * 16) ^ ((ln & 7) << 4));
                oaccA[nt] = mfma16(apA, bv, oaccA[nt]);
                oaccB[nt] = mfma16(apB, bv, oaccB[nt]);
            }
        }
        __builtin_amdgcn_s_setprio(0);
    }
    llocA += __shfl_xor(llocA, 16); llocA += __shfl_xor(llocA, 32);
    sloA  += __shfl_xor(sloA, 16);  sloA  += __shfl_xor(sloA, 32);
    shiA  += __shfl_xor(shiA, 16);  shiA  += __shfl_xor(shiA, 32);
    llocB += __shfl_xor(llocB, 16); llocB += __shfl_xor(llocB, 32);
    sloB  += __shfl_xor(sloB, 16);  sloB  += __shfl_xor(sloB, 32);
    shiB  += __shfl_xor(shiB, 16);  shiB  += __shfl_xor(shiB, 32);
    if (lg == 0) {
        prowA[0] = f2bf(sloA); prowA[254] = f2bf(shiA);
        prowB[0] = f2bf(sloB); prowB[254] = f2bf(shiB);
    }
    // O += Pagg @ table (B^T = tabT[d][j]); bt shared by both groups
#pragma unroll
    for (int ks8 = 0; ks8 < 8; ++ks8) {
        bf16x8 apA = ldg8(&Pagg[(w * 16 + ln) * 256 + ks8 * 32 + lg * 8]);
        bf16x8 apB = ldg8(&Pagg[(64 + w * 16 + ln) * 256 + ks8 * 32 + lg * 8]);
#pragma unroll
        for (int nt = 0; nt < 4; ++nt) {
            bf16x8 bt = ldg8(tabT + (size_t)(nt * 16 + ln) * 256 + ks8 * 32 + lg * 8);
            oaccA[nt] = mfma16(apA, bt, oaccA[nt]);
            oaccB[nt] = mfma16(apB, bt, oaccB[nt]);
        }
    }
    float rinvA[4], rinvB[4];
#pragma unroll
    for (int r = 0; r < 4; ++r) {
        rinvA[r] = 1.0f / __shfl(llocA, lg * 4 + r);
        rinvB[r] = 1.0f / __shfl(llocB, lg * 4 + r);
    }
    int b = bh >> 4, h = bh & 15;
#pragma unroll
    for (int nt = 0; nt < 4; ++nt) {
#pragma unroll
        for (int r = 0; r < 4; ++r) {
            int qoA = q0 + w * 16 + lg * 4 + r;
            out[((size_t)b * 1024 + qoA) * 1024 + h * 64 + nt * 16 + ln] = oaccA[nt][r] * rinvA[r];
            out[((size_t)b * 1024 + qoA + 64) * 1024 + h * 64 + nt * 16 + ln] = oaccB[nt][r] * rinvB[r];
        }
    }
}

extern "C" void kernel_launch(void* const* d_in, const int* in_sizes, int n_in,
                              void* d_out, int out_size, void* d_ws, size_t ws_size,
                              hipStream_t stream) {
    const float* hs  = (const float*)d_in[0];
    const float* Wq  = (const float*)d_in[1];
    const float* bq  = (const float*)d_in[2];
    const float* Wk  = (const float*)d_in[3];
    const float* bk  = (const float*)d_in[4];
    const float* Wv  = (const float*)d_in[5];
    const float* bv  = (const float*)d_in[6];
    const float* rel = (const float*)d_in[7];
    float* out = (float*)d_out;
    char* ws = (char*)d_ws;

    uint16_t* hs_bf = (uint16_t*)(ws);                // 8 MB   [4096][1024]
    uint16_t* W_bf  = (uint16_t*)(ws + 8388608);      // 6 MB   [3072][1024]
    uint16_t* q_bf  = (uint16_t*)(ws + 14680064);     // 8 MB   [64][1024][64]
    uint16_t* k_bf  = (uint16_t*)(ws + 23068672);     // 8 MB   [64][1024][64]
    uint16_t* vt_bf = (uint16_t*)(ws + 31457280);     // 8 MB   [64][64][1024]
    uint16_t* R_bf  = (uint16_t*)(ws + 48234496);     // 32 MB  [65536][256]
    uint16_t* tab   = (uint16_t*)(ws + 81788928);     // 32 KB  [256][64]
    uint16_t* tabT  = (uint16_t*)(ws + 81821696);     // 32 KB  [64][256]

    k_cast_all<<<3648, 256, 0, stream>>>(hs, Wq, Wk, Wv, rel, hs_bf, W_bf, tab, tabT);

    k_gemm_qkv3<<<768, 256, 0, stream>>>(hs_bf, W_bf, bq, bk, bv, q_bf, k_bf, vt_bf);

    k_attn_fused<<<512, 256, 0, stream>>>(q_bf, k_bf, vt_bf, R_bf, tab, tabT, out);
}